// Round 4
// baseline (115.796 us; speedup 1.0000x reference)
//
#include <hip/hip_runtime.h>
#include <hip/hip_bf16.h>
#include <math.h>

#define N_ROWS 8192
#define DIM    512           // fp8 row = 512 B
#define BM     128
#define BKB    128           // K-slab bytes per iter (128 fp8 elems = 4 MFMA ksteps)
#define NITER  (DIM / BKB)   // 4
#define NB     (N_ROWS / BM) // 64

typedef float floatx4 __attribute__((ext_vector_type(4)));

// ---------------- async global->LDS, 16B per lane ----------------
__device__ __forceinline__ void load16_to_lds(const void* g, void* l) {
    __builtin_amdgcn_global_load_lds(
        (const __attribute__((address_space(1))) unsigned int*)g,
        (__attribute__((address_space(3))) unsigned int*)l,
        16, 0, 0);
}

// ------------- Kernel 1: L2-normalize fp32 -> fp8 e4m3 (x16), zero d_out ----
__global__ __launch_bounds__(128) void normalize_kernel(
    const float* __restrict__ emb, unsigned char* __restrict__ out,
    float* __restrict__ loss_out)
{
    const int row = blockIdx.x;
    const int t   = threadIdx.x;
    if (row == 0 && t == 0) loss_out[0] = 0.0f;

    const float4* rp = (const float4*)(emb + (size_t)row * DIM);
    float4 v = rp[t];
    float ss = v.x*v.x + v.y*v.y + v.z*v.z + v.w*v.w;

    #pragma unroll
    for (int off = 32; off > 0; off >>= 1) ss += __shfl_down(ss, off);

    __shared__ float sred[2];
    if ((t & 63) == 0) sred[t >> 6] = ss;
    __syncthreads();
    const float tot = sred[0] + sred[1];
    const float rs  = 16.0f / fmaxf(sqrtf(tot), 1e-12f);   // normalize * 16

    int pk = 0;
    pk = __builtin_amdgcn_cvt_pk_fp8_f32(v.x * rs, v.y * rs, pk, false);
    pk = __builtin_amdgcn_cvt_pk_fp8_f32(v.z * rs, v.w * rs, pk, true);
    ((int*)(out + (size_t)row * DIM))[t] = pk;
}

// ------------- Kernel 2: fused fp8 E*E^T + contrastive loss ------------------
// LDS: double-buffered 128x128B slabs, row-major (stride 128 B), 16B chunk c of
// row r stored at slot c ^ (r&7). Fragment b64 reads spread exactly 4 dwords
// per bank (the b64 minimum) -> no conflict penalty. DMA realizes the swizzle
// on the global-address side (dest is contiguous lane*16).
__global__ __launch_bounds__(256) void gemmloss_kernel(
    const unsigned char* __restrict__ E, const int* __restrict__ labels,
    float* __restrict__ out)
{
    __shared__ __align__(16) unsigned char As[2][BM * BKB];  // 2 x 16 KB
    __shared__ __align__(16) unsigned char Bs[2][BM * BKB];  // 2 x 16 KB  (total 64 KB)

    // ---- decode triangular block id (br <= bc) ----
    const int bid = blockIdx.x;
    int br = (int)((2.0f * NB + 1.0f -
                    sqrtf((float)((2*NB+1)*(2*NB+1) - 8*bid))) * 0.5f);
    #define TRI_START(r) ((r)*NB - ((r)*((r)-1))/2)
    while (br > 0 && TRI_START(br) > bid) --br;
    while (TRI_START(br + 1) <= bid) ++br;
    const int bc = br + (bid - TRI_START(br));
    #undef TRI_START

    const int row0 = br * BM;
    const int col0 = bc * BM;

    const int t    = threadIdx.x;
    const int wave = t >> 6;
    const int lane = t & 63;
    const int wr   = wave >> 1;   // 0..1
    const int wc   = wave & 1;    // 0..1
    const int quad = lane >> 4;   // 0..3
    const int l16  = lane & 15;   // 0..15

    // ---- staging geometry: wave w stages rows [32w,32w+32) in 4 DMAs of 8 rows
    const int srow = lane >> 3;                 // 0..7 within 8-row group
    const int scg  = (lane & 7) ^ srow;         // swizzled global 16B chunk
    const unsigned char* gA0 =
        E + (size_t)(row0 + 32*wave + srow) * DIM + scg * 16;
    const unsigned char* gB0 =
        E + (size_t)(col0 + 32*wave + srow) * DIM + scg * 16;
    unsigned char* lA = &As[0][0] + (32 * wave) * BKB;   // +16384 for buf 1
    unsigned char* lB = &Bs[0][0] + (32 * wave) * BKB;

    // ---- fragment read offsets: frag(row r, kstep s, quad q) at
    //      r*128 + ((2s + (q>>1)) ^ (r&7))*16 + (q&1)*8 ;  r&7 == l16&7
    const int xr = l16 & 7;
    int offK[4];
    #pragma unroll
    for (int s = 0; s < 4; ++s)
        offK[s] = ((2*s + (quad >> 1)) ^ xr) * 16 + (quad & 1) * 8;
    const int rowA = (wr*64 + l16) * BKB;   // + mi*16*BKB
    const int rowB = (wc*64 + l16) * BKB;   // + ni*16*BKB

    floatx4 acc[4][4] = {};

    // ---- prologue stage: slab 0 into buffer 0 ----
    #pragma unroll
    for (int d = 0; d < 4; ++d) {
        load16_to_lds(gA0 + (size_t)d*8*DIM, lA + d*8*BKB);
        load16_to_lds(gB0 + (size_t)d*8*DIM, lB + d*8*BKB);
    }
    __syncthreads();   // vmcnt(0) drain: buf0 ready

    for (int it = 0; it < NITER; ++it) {
        const int b = it & 1;
        // issue next slab's DMAs into the other buffer (flight hidden by compute)
        if (it + 1 < NITER) {
            const int nb = b ^ 1;
            const unsigned char* gA = gA0 + (size_t)(it + 1) * BKB;
            const unsigned char* gB = gB0 + (size_t)(it + 1) * BKB;
            #pragma unroll
            for (int d = 0; d < 4; ++d) {
                load16_to_lds(gA + (size_t)d*8*DIM, lA + nb*16384 + d*8*BKB);
                load16_to_lds(gB + (size_t)d*8*DIM, lB + nb*16384 + d*8*BKB);
            }
        }

        const unsigned char* cA = &As[b][0];
        const unsigned char* cB = &Bs[b][0];
        #pragma unroll
        for (int s = 0; s < 4; ++s) {
            long af[4], bf[4];
            #pragma unroll
            for (int mi = 0; mi < 4; ++mi)
                af[mi] = *(const long*)(cA + rowA + mi*(16*BKB) + offK[s]);
            #pragma unroll
            for (int ni = 0; ni < 4; ++ni)
                bf[ni] = *(const long*)(cB + rowB + ni*(16*BKB) + offK[s]);
            #pragma unroll
            for (int mi = 0; mi < 4; ++mi)
                #pragma unroll
                for (int ni = 0; ni < 4; ++ni)
                    acc[mi][ni] = __builtin_amdgcn_mfma_f32_16x16x32_fp8_fp8(
                        af[mi], bf[ni], acc[mi][ni], 0, 0, 0);
        }
        __syncthreads();   // next buf DMAs drained; cur buf safe to overwrite
    }

    // ---- labels into registers (L2-hot, once per block) ----
    int rl[4][4], cl[4];
    #pragma unroll
    for (int mi = 0; mi < 4; ++mi)
        #pragma unroll
        for (int reg = 0; reg < 4; ++reg)
            rl[mi][reg] = labels[row0 + wr*64 + mi*16 + quad*4 + reg];
    #pragma unroll
    for (int ni = 0; ni < 4; ++ni)
        cl[ni] = labels[col0 + wc*64 + ni*16 + l16];

    // ---- epilogue: loss on the 64x64 wave subtile ----
    // C/D layout: col = lane&15, row = quad*4 + reg  [m89; dtype-independent]
    float lsum = 0.0f;
    #pragma unroll
    for (int mi = 0; mi < 4; ++mi) {
        const int tr_base = wr*64 + mi*16 + quad*4;
        #pragma unroll
        for (int ni = 0; ni < 4; ++ni) {
            const int tc = wc*64 + ni*16 + l16;
            const int gj = col0 + tc;
            #pragma unroll
            for (int reg = 0; reg < 4; ++reg) {
                const int gi = row0 + tr_base + reg;
                const float s = acc[mi][ni][reg] * (1.0f / 256.0f);
                if (gi != gj) {
                    if (rl[mi][reg] == cl[ni]) {
                        const float u = 1.0f - s;
                        lsum += u * u;
                    } else {
                        const float u = s - 0.5f;
                        if (u > 0.0f) lsum += u * u;
                    }
                }
            }
        }
    }

    lsum *= (br == bc) ? 1.0f : 2.0f;   // off-diagonal blocks count twice

    #pragma unroll
    for (int off = 32; off > 0; off >>= 1) lsum += __shfl_down(lsum, off);

    // block reduce through dead As, one atomic per block
    float* red = (float*)&As[0][0];
    if (lane == 0) red[wave] = lsum;
    __syncthreads();
    if (t == 0) {
        const float tot = red[0] + red[1] + red[2] + red[3];
        atomicAdd(out, tot * (1.0f / 67100672.0f));  // N*(N-1)
    }
}

// ---------------- launch ----------------
extern "C" void kernel_launch(void* const* d_in, const int* in_sizes, int n_in,
                              void* d_out, int out_size, void* d_ws, size_t ws_size,
                              hipStream_t stream)
{
    (void)in_sizes; (void)n_in; (void)out_size; (void)ws_size;

    const float* emb    = (const float*)d_in[0];
    const int*   labels = (const int*)d_in[1];
    float*       out    = (float*)d_out;
    unsigned char* E8   = (unsigned char*)d_ws;   // 4 MB fp8

    normalize_kernel<<<N_ROWS, 128, 0, stream>>>(emb, E8, out);

    const int nblocks = NB * (NB + 1) / 2;   // 2080
    gemmloss_kernel<<<nblocks, 256, 0, stream>>>(E8, labels, out);
}